// Round 11
// baseline (336.993 us; speedup 1.0000x reference)
//
#include <hip/hip_runtime.h>

#define NPB  16     // dense points per block
#define KNN  16     // neighbors
#define CIN  128
#define CF   160    // Cin + PE
#define MM   16     // weightnet out channels
#define PEC  32     // positional encoding channels
#define COUT 128
#define KDIM 2560   // CF * MM
#define LEPS 1e-5f

typedef __bf16 bf16x8 __attribute__((ext_vector_type(8)));
typedef float  f32x4  __attribute__((ext_vector_type(4)));
union U16x8 { uint4 u4; bf16x8 b; unsigned short us[8]; };

// LDS weight-bank offsets (floats)
#define SW_PE_W0   0
#define SW_PE_B0   96
#define SW_PE_G0   128
#define SW_PE_BE0  160
#define SW_PE_W1   192
#define SW_PE_B1   1216
#define SW_PE_G1   1248
#define SW_PE_BE1  1280
#define SW_WN_W0   1312
#define SW_WN_B0   1360
#define SW_WN_G0   1376
#define SW_WN_BE0  1392
#define SW_WN_W1   1408
#define SW_WN_B1   1664
#define SW_WN_G1   1680
#define SW_WN_BE1  1696
#define SW_WN_W2   1712
#define SW_WN_B2   1968
#define SW_WN_G2   1984
#define SW_WN_BE2  2000
#define SW_TOTAL   2016

__device__ __forceinline__ float bf2f(unsigned short b){
  union { unsigned int u; float f; } x; x.u = ((unsigned int)b) << 16; return x.f;
}
__device__ __forceinline__ unsigned short f2bf(float f){
  union { float f; unsigned int u; } x; x.f = f;
  unsigned int r = (x.u + 0x7fffu + ((x.u >> 16) & 1u)) >> 16;
  return (unsigned short)r;
}
// HW RTNE convert via __bf16 cast
__device__ __forceinline__ unsigned short f2b(float f){
  union { __bf16 h; unsigned short u; } v; v.h = (__bf16)f; return v.u;
}
__device__ __forceinline__ float rsum16(float v){
  v += __shfl_xor(v, 8, 16);
  v += __shfl_xor(v, 4, 16);
  v += __shfl_xor(v, 2, 16);
  v += __shfl_xor(v, 1, 16);
  return v;
}
__device__ __forceinline__ float rsum32(float v){
  v += __shfl_xor(v, 16, 32);
  v += __shfl_xor(v, 8, 32);
  v += __shfl_xor(v, 4, 32);
  v += __shfl_xor(v, 2, 32);
  v += __shfl_xor(v, 1, 32);
  return v;
}
__device__ __forceinline__ float lrelu(float v){ return v >= 0.f ? v : 0.1f * v; }

template<int N>
__device__ __forceinline__ void ln_inlane(float* v, const float* g, const float* be, bool act){
  float mu = 0.f;
#pragma unroll
  for (int i = 0; i < N; ++i) mu += v[i];
  mu *= (1.f / N);
  float var = 0.f;
#pragma unroll
  for (int i = 0; i < N; ++i) { float d = v[i] - mu; var += d * d; }
  const float rs = rsqrtf(var * (1.f / N) + LEPS);
#pragma unroll
  for (int i = 0; i < N; ++i) {
    float y = (v[i] - mu) * rs * g[i] + be[i];
    v[i] = act ? lrelu(y) : y;
  }
}

// ============================================================================
// Kernel PREP: blocks [0,160) pack lin_w -> wpack fragments; rest convert
// sparse_feats f32 -> bf16 (2.56 MB; fits per-XCD L2 for the gathers).
// wpack fragment (s,tt,lane,j): i' = s*32+(lane>>4)*8+j, n = tt*16+(lane&15),
// at wpack[((s*8+tt)*64+lane)*8 + j], where
// i' = P*512 + c16*32 + q*8 + ctl*4 + r, c = P*32+ctl*16+c16, m = q*4+r,
// lin_w row = c*16 + m.  (Same contract the einsum's D emitter uses.)
// ============================================================================
__global__ __launch_bounds__(256)
void pct_prep(const float* __restrict__ lin_w, unsigned short* __restrict__ wpack,
              const float* __restrict__ sf, unsigned short* __restrict__ sfb16,
              const int n4)
{
  const int bid = blockIdx.x;
  if (bid < 160) {
    const int u    = bid * 256 + threadIdx.x;   // 0..40959
    const int lane = u & 63;
    const int tt   = (u >> 6) & 7;
    const int s    = u >> 9;
    const int ipb  = s * 32 + ((lane >> 4) * 8);
    const int nn   = tt * 16 + (lane & 15);
    unsigned short v[8];
#pragma unroll
    for (int j = 0; j < 8; ++j) {
      const int ip  = ipb + j;
      const int r   = ip & 3;
      const int ctl = (ip >> 2) & 1;
      const int qq  = (ip >> 3) & 3;
      const int c16 = (ip >> 5) & 15;
      const int P   = ip >> 9;
      const int c   = P * 32 + ctl * 16 + c16;
      const int m   = qq * 4 + r;
      v[j] = f2bf(lin_w[(long)(c * MM + m) * COUT + nn]);
    }
    *(uint4*)(wpack + (long)u * 8) = *(uint4*)v;
  } else {
    const int i = (bid - 160) * 256 + threadIdx.x;
    if (i >= n4) return;
    const float4 v = ((const float4*)sf)[i];
    union { unsigned short us[4]; uint2 u; } r;
    r.us[0] = f2b(v.x); r.us[1] = f2b(v.y); r.us[2] = f2b(v.z); r.us[3] = f2b(v.w);
    ((uint2*)sfb16)[i] = r.u;
  }
}

// ============================================================================
// Kernel ALL (nets + einsum + gemm fully fused). Round-10 post-mortem: eg is
// structurally stuck at 111-117 us (occupancy r9 and MFMA-ILP r10 both null);
// the bigger cost is the ~175 us OUTSIDE eg: pct_nets + 61 MB fragw
// round-trip + launch gap, which exist only to hand wave-local fragments to
// eg. Here nets runs in-kernel: nets compute (verbatim) -> pack STRAIGHT to
// the af/pe0/pe1 registers (same uint4s eg reloaded from fragw; each lane
// now gathers both pe halves) -> barrier -> feats staging overwrites the
// nets LDS region (union) -> einsum/gemm chunks (r8 2-chain gemm + r9/r10
// verified feat source-swizzle) -> epilogue. LDS peak unchanged at 80 KB
// (2 blocks/CU); fragw eliminated.
// ============================================================================
__global__ __launch_bounds__(256)
void pct_all(
    const float* __restrict__ sparse_xyz,
    const int* __restrict__ nei_inds,
    const float* __restrict__ dense_xyz,
    const unsigned short* __restrict__ sfb16,
    const float* __restrict__ pe_w0, const float* __restrict__ pe_b0,
    const float* __restrict__ pe_g0, const float* __restrict__ pe_be0,
    const float* __restrict__ pe_w1, const float* __restrict__ pe_b1,
    const float* __restrict__ pe_g1, const float* __restrict__ pe_be1,
    const float* __restrict__ wn_w0, const float* __restrict__ wn_b0,
    const float* __restrict__ wn_g0, const float* __restrict__ wn_be0,
    const float* __restrict__ wn_w1, const float* __restrict__ wn_b1,
    const float* __restrict__ wn_g1, const float* __restrict__ wn_be1,
    const float* __restrict__ wn_w2, const float* __restrict__ wn_b2,
    const float* __restrict__ wn_g2, const float* __restrict__ wn_be2,
    const unsigned short* __restrict__ wpack,
    const float* __restrict__ lin_b, const float* __restrict__ lin_g,
    const float* __restrict__ lin_be, const float* __restrict__ dense_feats,
    float* __restrict__ out)
{
  __shared__ __align__(16) union FU {
    struct {
      float sw[SW_TOTAL];                 // 8064 B
      unsigned short wtsf[16 * 256];      // 8 KB A-frags
      unsigned short pef[16 * 512];       // 16 KB [p][k][32c]
    } n;                                  // 32640 B (nets phase)
    unsigned short feats[16][2048];       // 64 KB (einsum phase, swizzled slots)
    float outs[16][132];                  // epilogue tile
  } fu;
  __shared__ __align__(16) unsigned short aL[16][512];   // 16 KB bridge

  const int t     = threadIdx.x;
  const int nbase = blockIdx.x * NPB;
  const int lane  = t & 63;
  const int wave  = t >> 6;         // 0..3
  const int q     = lane >> 4;      // 0..3
  const int mq    = lane & 15;
  const int q1    = q & 1;
  const int mqh   = mq >> 3, mql = mq & 7;

  // neighbor indices for staging (instr t4 of point i uses idx[t4*4 + q])
  int idxall[4][4];
#pragma unroll
  for (int i = 0; i < 4; ++i)
#pragma unroll
    for (int t4 = 0; t4 < 4; ++t4)
      idxall[i][t4] = nei_inds[(nbase + wave*4 + i) * KNN + t4*4 + q];

  // ---- stage net weights in LDS ----
  float* sw = fu.n.sw;
  for (int i = t; i < 96;   i += 256) sw[SW_PE_W0 + i] = pe_w0[i];
  for (int i = t; i < 32;   i += 256) {
    sw[SW_PE_B0 + i] = pe_b0[i];  sw[SW_PE_G0 + i] = pe_g0[i];  sw[SW_PE_BE0 + i] = pe_be0[i];
    sw[SW_PE_B1 + i] = pe_b1[i];  sw[SW_PE_G1 + i] = pe_g1[i];  sw[SW_PE_BE1 + i] = pe_be1[i];
  }
  for (int i = t; i < 1024; i += 256) sw[SW_PE_W1 + i] = pe_w1[i];
  for (int i = t; i < 48;   i += 256) sw[SW_WN_W0 + i] = wn_w0[i];
  for (int i = t; i < 16;   i += 256) {
    sw[SW_WN_B0 + i] = wn_b0[i];  sw[SW_WN_G0 + i] = wn_g0[i];  sw[SW_WN_BE0 + i] = wn_be0[i];
    sw[SW_WN_B1 + i] = wn_b1[i];  sw[SW_WN_G1 + i] = wn_g1[i];  sw[SW_WN_BE1 + i] = wn_be1[i];
    sw[SW_WN_B2 + i] = wn_b2[i];  sw[SW_WN_G2 + i] = wn_g2[i];  sw[SW_WN_BE2 + i] = wn_be2[i];
  }
  for (int i = t; i < 256;  i += 256) { sw[SW_WN_W1 + i] = wn_w1[i]; sw[SW_WN_W2 + i] = wn_w2[i]; }
  __syncthreads();

  // ---- nets compute: thread (p = t>>4, kk = t&15); wave-local (p>>2==wave) ----
  {
    const int p  = t >> 4;
    const int kk = t & 15;
    const int n  = nbase + p;
    const int idx = nei_inds[n * KNN + kk];
    const float x0 = sparse_xyz[idx*3+0] - dense_xyz[n*3+0];
    const float x1 = sparse_xyz[idx*3+1] - dense_xyz[n*3+1];
    const float x2 = sparse_xyz[idx*3+2] - dense_xyz[n*3+2];

    // pe layer0 (3->32) + LN + act
    float h[32];
#pragma unroll
    for (int c = 0; c < 32; ++c)
      h[c] = x0*sw[SW_PE_W0+c] + x1*sw[SW_PE_W0+32+c] + x2*sw[SW_PE_W0+64+c] + sw[SW_PE_B0+c];
    ln_inlane<32>(h, &sw[SW_PE_G0], &sw[SW_PE_BE0], true);

    // pe layer1 (32->32) + LN (no act)
    float z[32];
#pragma unroll
    for (int c = 0; c < 32; ++c) z[c] = sw[SW_PE_B1 + c];
#pragma unroll 4
    for (int j = 0; j < 32; ++j) {
      const float hj = h[j];
#pragma unroll
      for (int c = 0; c < 32; ++c) z[c] += hj * sw[SW_PE_W1 + j*32 + c];
    }
    ln_inlane<32>(z, &sw[SW_PE_G1], &sw[SW_PE_BE1], false);
    {
      union { unsigned short us[32]; uint4 u4[4]; } zb;
#pragma unroll
      for (int c = 0; c < 32; ++c) zb.us[c] = f2b(z[c]);
      unsigned short* pp_ = fu.n.pef + p*512 + kk*32;   // [p][k][32c]
#pragma unroll
      for (int j = 0; j < 4; ++j) *(uint4*)(pp_ + j*8) = zb.u4[j];
    }

    // wn layer0 (3->16) + LN + act
    float w[16];
#pragma unroll
    for (int m = 0; m < 16; ++m)
      w[m] = x0*sw[SW_WN_W0+m] + x1*sw[SW_WN_W0+16+m] + x2*sw[SW_WN_W0+32+m] + sw[SW_WN_B0+m];
    ln_inlane<16>(w, &sw[SW_WN_G0], &sw[SW_WN_BE0], true);

    // wn layer1 (16->16) + LN + act
    float z2[16];
#pragma unroll
    for (int m = 0; m < 16; ++m) z2[m] = sw[SW_WN_B1 + m];
#pragma unroll 4
    for (int j = 0; j < 16; ++j) {
      const float wj = w[j];
#pragma unroll
      for (int m = 0; m < 16; ++m) z2[m] += wj * sw[SW_WN_W1 + j*16 + m];
    }
    ln_inlane<16>(z2, &sw[SW_WN_G1], &sw[SW_WN_BE1], true);

    // wn layer2 (16->16) + LN (no act)
#pragma unroll
    for (int m = 0; m < 16; ++m) w[m] = sw[SW_WN_B2 + m];
#pragma unroll 4
    for (int j = 0; j < 16; ++j) {
      const float wj = z2[j];
#pragma unroll
      for (int m = 0; m < 16; ++m) w[m] += wj * sw[SW_WN_W2 + j*16 + m];
    }
    ln_inlane<16>(w, &sw[SW_WN_G2], &sw[SW_WN_BE2], false);
    // A-fragment store: slot lane L=(kk>>3)*16+m holds wts[k=(L>>4)*8+j][m=L&15]
    {
      unsigned short* wf = fu.n.wtsf + p*256 + ((kk >> 3) << 7) + (kk & 7);
#pragma unroll
      for (int m = 0; m < 16; ++m) wf[m*8] = f2b(w[m]);
    }
  }
  // NO barrier: wave w wrote wtsf/pef rows for points 4w..4w+3 and packs the
  // same (same-wave DS ops complete in order — the pattern 7 rounds verified).

  // ---- pack to REGISTERS (replaces fragw round-trip) ----
  U16x8 af[4], pe0[4], pe1[4];
  const uint4 zero4 = {0u, 0u, 0u, 0u};
  {
    const int l2 = lane & 31;
#pragma unroll
    for (int i = 0; i < 4; ++i) {
      const int p = wave*4 + i;
      af[i].u4 = (lane < 32) ? *(const uint4*)(fu.n.wtsf + p*256 + lane*8) : zero4;
      U16x8 e0, e1;
#pragma unroll
      for (int j = 0; j < 8; ++j) {
        const int ro = p*512 + ((l2 >> 4)*8 + j)*32 + (l2 & 15);
        e0.us[j] = fu.n.pef[ro];
        e1.us[j] = fu.n.pef[ro + 16];
      }
      pe0[i] = e0; pe1[i] = e1;
    }
  }
  __syncthreads();   // all waves done reading fu.n before feats overwrite

  // ---- feats staging: 16 glds, source-swizzled (slot mq <- mq^((t4>>1)<<1)) ----
#pragma unroll
  for (int i = 0; i < 4; ++i) {
    const int p = wave*4 + i;
#pragma unroll
    for (int t4 = 0; t4 < 4; ++t4)
      __builtin_amdgcn_global_load_lds(
          (const void*)(sfb16 + (size_t)idxall[i][t4] * CIN
                        + ((mq ^ ((t4 >> 1) << 1)) * 8)),
          (void*)((char*)fu.feats[p] + t4 * 1024), 16, 0, 0);
  }
  __syncthreads();   // feats resident (full drain via barrier semantics)

  f32x4 acc0 = {0.f,0.f,0.f,0.f}, acc1 = {0.f,0.f,0.f,0.f};
  const unsigned short* wpl = wpack + ((size_t)(wave*2) * 64 + lane) * 8;

#pragma unroll 1
  for (int P = 0; P < 5; ++P) {
    // ---- einsum phase: D chunk for own 4 points -> aL ----
#pragma unroll
    for (int i = 0; i < 4; ++i) {
      const int p = wave*4 + i;
      f32x4 a0 = {0.f,0.f,0.f,0.f}, a1 = {0.f,0.f,0.f,0.f};
      if (P < 4) {
        // elem (k = q1*8+j, c = ct*16+mq): slot = (2*ct + mqh) ^ (q1<<1)
        const int slot0 = (4*P     + mqh) ^ (q1 << 1);
        const int slot1 = (4*P + 2 + mqh) ^ (q1 << 1);
        const unsigned short* fb = &fu.feats[p][0] + q1*1024 + mql;
        U16x8 b0_, b1_;
#pragma unroll
        for (int j = 0; j < 8; ++j) b0_.us[j] = fb[j*128 + slot0*8];
#pragma unroll
        for (int j = 0; j < 8; ++j) b1_.us[j] = fb[j*128 + slot1*8];
        a0 = __builtin_amdgcn_mfma_f32_16x16x32_bf16(af[i].b, b0_.b, a0, 0, 0, 0);
        a1 = __builtin_amdgcn_mfma_f32_16x16x32_bf16(af[i].b, b1_.b, a1, 0, 0, 0);
      } else {
        a0 = __builtin_amdgcn_mfma_f32_16x16x32_bf16(af[i].b, pe0[i].b, a0, 0, 0, 0);
        a1 = __builtin_amdgcn_mfma_f32_16x16x32_bf16(af[i].b, pe1[i].b, a1, 0, 0, 0);
      }
      // D write: lane holds D[m=q*4+r][c-slice]; chunk elem off = mq*32+q*8+ctl*4+r
      union { unsigned short us[8]; uint4 u4; } o;
#pragma unroll
      for (int r = 0; r < 4; ++r) { o.us[r] = f2b(a0[r]); o.us[4+r] = f2b(a1[r]); }
      *(uint4*)((char*)aL[p] + ((mq*64 + q*16) ^ ((p & 7) << 4))) = o.u4;
    }
    __syncthreads();   // aL chunk complete

    // ---- gemm phase: 16 k-tiles of this chunk (r8 structure) ----
#pragma unroll
    for (int s = 0; s < 16; ++s) {
      const int sg = P*16 + s;
      U16x8 af2;
      af2.u4 = *(const uint4*)((char*)aL[mq] + ((s*64 + q*16) ^ ((mq & 7) << 4)));
      const unsigned short* wpb = wpl + (size_t)sg * 4096;
      U16x8 b0_, b1_;
      b0_.u4 = *(const uint4*)(wpb);
      b1_.u4 = *(const uint4*)(wpb + 512);
      acc0 = __builtin_amdgcn_mfma_f32_16x16x32_bf16(af2.b, b0_.b, acc0, 0, 0, 0);
      acc1 = __builtin_amdgcn_mfma_f32_16x16x32_bf16(af2.b, b1_.b, acc1, 0, 0, 0);
    }
    __syncthreads();   // done reading aL before next chunk overwrites
  }

  // ---- scatter: C[row=q*4+r][col=(2w+j)*16+mq], rows = block points ----
#pragma unroll
  for (int r = 0; r < 4; ++r) {
    fu.outs[q*4 + r][(wave*2    )*16 + mq] = acc0[r];
    fu.outs[q*4 + r][(wave*2 + 1)*16 + mq] = acc1[r];
  }
  __syncthreads();

  // ---- epilogue: 16 threads/point, 8 cols each ----
  {
    const int p   = t >> 4;
    const int l16 = t & 15;
    const int n   = nbase + p;
    float v[8];
#pragma unroll
    for (int i = 0; i < 2; ++i) {
      const int cb = (i*16 + l16) * 4;
      const float4 r  = *(const float4*)(&fu.outs[p][cb]);
      const float4 bb = *(const float4*)(lin_b + cb);
      v[i*4+0] = r.x + bb.x; v[i*4+1] = r.y + bb.y;
      v[i*4+2] = r.z + bb.z; v[i*4+3] = r.w + bb.w;
    }
    float sum = 0.f;
#pragma unroll
    for (int i = 0; i < 8; ++i) sum += v[i];
    const float mu = rsum16(sum) * (1.f/128.f);
    float qs = 0.f;
#pragma unroll
    for (int i = 0; i < 8; ++i) { float d = v[i] - mu; qs += d*d; }
    const float rs = rsqrtf(rsum16(qs) * (1.f/128.f) + LEPS);
#pragma unroll
    for (int i = 0; i < 2; ++i) {
      const int cb = (i*16 + l16) * 4;
      const float4 g  = *(const float4*)(lin_g  + cb);
      const float4 be = *(const float4*)(lin_be + cb);
      const float4 df = *(const float4*)(dense_feats + (long)n*COUT + cb);
      float4 y;
      y.x = lrelu((v[i*4+0]-mu)*rs*g.x + be.x) + df.x;
      y.y = lrelu((v[i*4+1]-mu)*rs*g.y + be.y) + df.y;
      y.z = lrelu((v[i*4+2]-mu)*rs*g.z + be.z) + df.z;
      y.w = lrelu((v[i*4+3]-mu)*rs*g.w + be.w) + df.w;
      *(float4*)(out + (long)n*COUT + cb) = y;
    }
  }
}

// ============================================================================
// Last-resort fallback: fully-fused kernel (used if ws_size is too small)
// ============================================================================
__global__ __launch_bounds__(256)
void pct_fused(
    const float* __restrict__ sparse_xyz,
    const float* __restrict__ sparse_feats,
    const int* __restrict__ nei_inds,
    const float* __restrict__ dense_xyz,
    const float* __restrict__ dense_feats,
    const float* __restrict__ pe_w0, const float* __restrict__ pe_b0,
    const float* __restrict__ pe_g0, const float* __restrict__ pe_be0,
    const float* __restrict__ pe_w1, const float* __restrict__ pe_b1,
    const float* __restrict__ pe_g1, const float* __restrict__ pe_be1,
    const float* __restrict__ wn_w0, const float* __restrict__ wn_b0,
    const float* __restrict__ wn_g0, const float* __restrict__ wn_be0,
    const float* __restrict__ wn_w1, const float* __restrict__ wn_b1,
    const float* __restrict__ wn_g1, const float* __restrict__ wn_be1,
    const float* __restrict__ wn_w2, const float* __restrict__ wn_b2,
    const float* __restrict__ wn_g2, const float* __restrict__ wn_be2,
    const float* __restrict__ lin_w, const float* __restrict__ lin_b,
    const float* __restrict__ lin_g, const float* __restrict__ lin_be,
    float* __restrict__ out)
{
  __shared__ __align__(16) unsigned short feat_s[KNN][CF];
  __shared__ float wts_s[KNN][MM];
  __shared__ float loc_s[KNN][3];
  __shared__ int   nei_s[KNN];
  __shared__ __align__(16) unsigned short out_tile[CF*MM][8];

  const int t  = threadIdx.x;
  const int n0 = blockIdx.x * 8;
  const int k  = t >> 4;
  const int l  = t & 15;

#pragma unroll 1
  for (int p = 0; p < 8; ++p) {
    const int n = n0 + p;
    if (t < KNN) {
      int idx = nei_inds[n*KNN + t];
      nei_s[t] = idx;
      loc_s[t][0] = sparse_xyz[idx*3+0] - dense_xyz[n*3+0];
      loc_s[t][1] = sparse_xyz[idx*3+1] - dense_xyz[n*3+1];
      loc_s[t][2] = sparse_xyz[idx*3+2] - dense_xyz[n*3+2];
    }
    __syncthreads();
    {
      const int gk = t >> 4;
      const int c8 = (t & 15) * 8;
      const float* src = sparse_feats + (long)nei_s[gk]*CIN + c8;
      const float4 va = *(const float4*)(src);
      const float4 vb = *(const float4*)(src + 4);
      unsigned short* dst = &feat_s[gk][c8];
      dst[0] = f2bf(va.x); dst[1] = f2bf(va.y); dst[2] = f2bf(va.z); dst[3] = f2bf(va.w);
      dst[4] = f2bf(vb.x); dst[5] = f2bf(vb.y); dst[6] = f2bf(vb.z); dst[7] = f2bf(vb.w);
    }
    const float x0 = loc_s[k][0], x1 = loc_s[k][1], x2 = loc_s[k][2];
    const int c0 = l, c1 = l + 16;
    float ha = x0*pe_w0[0*PEC+c0] + x1*pe_w0[1*PEC+c0] + x2*pe_w0[2*PEC+c0] + pe_b0[c0];
    float hb = x0*pe_w0[0*PEC+c1] + x1*pe_w0[1*PEC+c1] + x2*pe_w0[2*PEC+c1] + pe_b0[c1];
    {
      float mu = rsum16(ha + hb) * (1.f/32.f);
      float da = ha - mu, db = hb - mu;
      float q  = rsum16(da*da + db*db);
      float rs = rsqrtf(q*(1.f/32.f) + LEPS);
      ha = lrelu(da*rs*pe_g0[c0] + pe_be0[c0]);
      hb = lrelu(db*rs*pe_g0[c1] + pe_be0[c1]);
    }
    float za = pe_b1[c0], zb = pe_b1[c1];
#pragma unroll
    for (int j = 0; j < 16; ++j) {
      float va = __shfl(ha, j, 16);
      float vb = __shfl(hb, j, 16);
      za += va * pe_w1[j*PEC + c0] + vb * pe_w1[(j+16)*PEC + c0];
      zb += va * pe_w1[j*PEC + c1] + vb * pe_w1[(j+16)*PEC + c1];
    }
    {
      float mu = rsum16(za + zb) * (1.f/32.f);
      float da = za - mu, db = zb - mu;
      float q  = rsum16(da*da + db*db);
      float rs = rsqrtf(q*(1.f/32.f) + LEPS);
      feat_s[k][CIN + c0] = f2bf(da*rs*pe_g1[c0] + pe_be1[c0]);
      feat_s[k][CIN + c1] = f2bf(db*rs*pe_g1[c1] + pe_be1[c1]);
    }
    float w0v = x0*wn_w0[0*MM+l] + x1*wn_w0[1*MM+l] + x2*wn_w0[2*MM+l] + wn_b0[l];
    {
      float mu = rsum16(w0v) * (1.f/16.f);
      float d  = w0v - mu;
      float rs = rsqrtf(rsum16(d*d)*(1.f/16.f) + LEPS);
      w0v = lrelu(d*rs*wn_g0[l] + wn_be0[l]);
    }
    float w1v = wn_b1[l];
#pragma unroll
    for (int j = 0; j < 16; ++j)
      w1v += __shfl(w0v, j, 16) * wn_w1[j*MM + l];
    {
      float mu = rsum16(w1v) * (1.f/16.f);
      float d  = w1v - mu;
      float rs = rsqrtf(rsum16(d*d)*(1.f/16.f) + LEPS);
      w1v = lrelu(d*rs*wn_g1[l] + wn_be1[l]);
    }
    float w2v = wn_b2[l];
#pragma unroll
    for (int j = 0; j < 16; ++j)
      w2v += __shfl(w1v, j, 16) * wn_w2[j*MM + l];
    {
      float mu = rsum16(w2v) * (1.f/16.f);
      float d  = w2v - mu;
      float rs = rsqrtf(rsum16(d*d)*(1.f/16.f) + LEPS);
      w2v = d*rs*wn_g2[l] + wn_be2[l];
    }
    wts_s[k][l] = w2v;
    __syncthreads();
    {
      const int m = t & 15;
      const int g = t >> 4;
      float wv[KNN];
#pragma unroll
      for (int kk = 0; kk < KNN; ++kk) wv[kk] = wts_s[kk][m];
#pragma unroll
      for (int j = 0; j < 10; ++j) {
        const int c = g*10 + j;
        float acc = 0.f;
#pragma unroll
        for (int kk = 0; kk < KNN; ++kk)
          acc += bf2f(feat_s[kk][c]) * wv[kk];
        out_tile[c*MM + m][p] = f2bf(acc);
      }
    }
    __syncthreads();
  }
  {
    const int h  = t >> 6;
    const int o0 = (t & 63) * 2;
    float acc0[8], acc1[8];
#pragma unroll
    for (int p = 0; p < 8; ++p) { acc0[p] = 0.f; acc1[p] = 0.f; }
    const int i0 = h * 640;
    for (int i = i0; i < i0 + 640; ++i) {
      const float2 wv = *(const float2*)(lin_w + (long)i*COUT + o0);
      const float wa = wv.x;
      const float wc = wv.y;
      const uint4 r = *(const uint4*)(&out_tile[i][0]);
      const float f0 = bf2f((unsigned short)(r.x & 0xffffu));
      const float f1 = bf2f((unsigned short)(r.x >> 16));
      const float g2 = bf2f((unsigned short)(r.y & 0xffffu));
      const float g3 = bf2f((unsigned short)(r.y >> 16));
      const float g4 = bf2f((unsigned short)(r.z & 0xffffu));
      const float g5 = bf2f((unsigned short)(r.z >> 16));
      const float g6 = bf2f((unsigned short)(r.w & 0xffffu));
      const float g7 = bf2f((unsigned short)(r.w >> 16));
      acc0[0] += f0*wa; acc1[0] += f0*wc;
      acc0[1] += f1*wa; acc1[1] += f1*wc;
      acc0[2] += g2*wa; acc1[2] += g2*wc;
      acc0[3] += g3*wa; acc1[3] += g3*wc;
      acc0[4] += g4*wa; acc1[4] += g4*wc;
      acc0[5] += g5*wa; acc1[5] += g5*wc;
      acc0[6] += g6*wa; acc1[6] += g6*wc;
      acc0[7] += g7*wa; acc1[7] += g7*wc;
    }
    __syncthreads();
    float* red = (float*)&out_tile[0][0];
#pragma unroll
    for (int p = 0; p < 8; ++p) {
      red[((h*8 + p) << 7) + o0    ] = acc0[p];
      red[((h*8 + p) << 7) + o0 + 1] = acc1[p];
    }
    __syncthreads();
    const int p2 = t >> 5, l2 = t & 31;
    const int n  = n0 + p2;
    float v[4];
#pragma unroll
    for (int j = 0; j < 4; ++j) {
      const int o = l2 + (j << 5);
      float sv = red[((0*8 + p2) << 7) + o] + red[((1*8 + p2) << 7) + o]
               + red[((2*8 + p2) << 7) + o] + red[((3*8 + p2) << 7) + o];
      v[j] = sv + lin_b[o];
    }
    float mu = rsum32(v[0] + v[1] + v[2] + v[3]) * (1.f/128.f);
    float q = 0.f;
#pragma unroll
    for (int j = 0; j < 4; ++j) { float d = v[j] - mu; q += d*d; }
    float rs = rsqrtf(rsum32(q) * (1.f/128.f) + LEPS);
#pragma unroll
    for (int j = 0; j < 4; ++j) {
      const int o = l2 + (j << 5);
      float y = (v[j] - mu) * rs * lin_g[o] + lin_be[o];
      y = lrelu(y);
      y += dense_feats[n*COUT + o];
      out[n*COUT + o] = y;
    }
  }
}

extern "C" void kernel_launch(void* const* d_in, const int* in_sizes, int n_in,
                              void* d_out, int out_size, void* d_ws, size_t ws_size,
                              hipStream_t stream) {
  const int Nd = in_sizes[2] / KNN;    // 40000
  const int Ns = in_sizes[1] / CIN;    // 10000
  const size_t w_bytes = (size_t)KDIM * COUT * 2;     // 655 KB
  const size_t f_bytes = (size_t)Ns * CIN * 2;        // 2.56 MB
  const bool use_split = (ws_size >= w_bytes + f_bytes)
                         && (Nd % NPB == 0) && ((Ns * CIN) % 4 == 0);

  if (use_split) {
    unsigned short* wpack = (unsigned short*)d_ws;
    unsigned short* sfb16 = (unsigned short*)((char*)d_ws + w_bytes);

    const int n4 = Ns * CIN / 4;
    pct_prep<<<dim3(160 + (n4 + 255)/256), dim3(256), 0, stream>>>(
      (const float*)d_in[27], wpack, (const float*)d_in[1], sfb16, n4);

    pct_all<<<dim3(Nd / NPB), dim3(256), 0, stream>>>(
      (const float*)d_in[0],  (const int*)d_in[2],  (const float*)d_in[4],
      sfb16,
      (const float*)d_in[7],  (const float*)d_in[8],  (const float*)d_in[9],  (const float*)d_in[10],
      (const float*)d_in[11], (const float*)d_in[12], (const float*)d_in[13], (const float*)d_in[14],
      (const float*)d_in[15], (const float*)d_in[16], (const float*)d_in[17], (const float*)d_in[18],
      (const float*)d_in[19], (const float*)d_in[20], (const float*)d_in[21], (const float*)d_in[22],
      (const float*)d_in[23], (const float*)d_in[24], (const float*)d_in[25], (const float*)d_in[26],
      wpack,
      (const float*)d_in[28], (const float*)d_in[29], (const float*)d_in[30],
      (const float*)d_in[6], (float*)d_out);
  } else {
    pct_fused<<<dim3(Nd / 8), dim3(256), 0, stream>>>(
      (const float*)d_in[0],  (const float*)d_in[1],  (const int*)d_in[2],
      (const float*)d_in[4],  (const float*)d_in[6],
      (const float*)d_in[7],  (const float*)d_in[8],  (const float*)d_in[9],  (const float*)d_in[10],
      (const float*)d_in[11], (const float*)d_in[12], (const float*)d_in[13], (const float*)d_in[14],
      (const float*)d_in[15], (const float*)d_in[16], (const float*)d_in[17], (const float*)d_in[18],
      (const float*)d_in[19], (const float*)d_in[20], (const float*)d_in[21], (const float*)d_in[22],
      (const float*)d_in[23], (const float*)d_in[24], (const float*)d_in[25], (const float*)d_in[26],
      (const float*)d_in[27], (const float*)d_in[28], (const float*)d_in[29], (const float*)d_in[30],
      (float*)d_out);
  }
}

// Round 12
// 281.539 us; speedup vs baseline: 1.1970x; 1.1970x over previous
//
#include <hip/hip_runtime.h>

#define NPB  16     // dense points per block
#define KNN  16     // neighbors
#define CIN  128
#define CF   160    // Cin + PE
#define MM   16     // weightnet out channels
#define PEC  32     // positional encoding channels
#define COUT 128
#define KDIM 2560   // CF * MM
#define FRE  768    // fragw elems per point: af(256) + pe0(256) + pe1(256)
#define LEPS 1e-5f

typedef __bf16 bf16x8 __attribute__((ext_vector_type(8)));
typedef float  f32x4  __attribute__((ext_vector_type(4)));
union U16x8 { uint4 u4; bf16x8 b; unsigned short us[8]; };

// LDS weight-bank offsets (floats)
#define SW_PE_W0   0
#define SW_PE_B0   96
#define SW_PE_G0   128
#define SW_PE_BE0  160
#define SW_PE_B1   192
#define SW_PE_G1   224
#define SW_PE_BE1  256
#define SW_WN_W0   288
#define SW_WN_B0   336
#define SW_WN_G0   352
#define SW_WN_BE0  368
#define SW_WN_W1   384
#define SW_WN_B1   640
#define SW_WN_G1   656
#define SW_WN_BE1  672
#define SW_WN_W2   688
#define SW_WN_B2   944
#define SW_WN_G2   960
#define SW_WN_BE2  976
#define SW_TOTAL   992

__device__ __forceinline__ float bf2f(unsigned short b){
  union { unsigned int u; float f; } x; x.u = ((unsigned int)b) << 16; return x.f;
}
__device__ __forceinline__ unsigned short f2bf(float f){
  union { float f; unsigned int u; } x; x.f = f;
  unsigned int r = (x.u + 0x7fffu + ((x.u >> 16) & 1u)) >> 16;
  return (unsigned short)r;
}
// HW RTNE convert via __bf16 cast
__device__ __forceinline__ unsigned short f2b(float f){
  union { __bf16 h; unsigned short u; } v; v.h = (__bf16)f; return v.u;
}
__device__ __forceinline__ float rsum16(float v){
  v += __shfl_xor(v, 8, 16);
  v += __shfl_xor(v, 4, 16);
  v += __shfl_xor(v, 2, 16);
  v += __shfl_xor(v, 1, 16);
  return v;
}
__device__ __forceinline__ float rsum32(float v){
  v += __shfl_xor(v, 16, 32);
  v += __shfl_xor(v, 8, 32);
  v += __shfl_xor(v, 4, 32);
  v += __shfl_xor(v, 2, 32);
  v += __shfl_xor(v, 1, 32);
  return v;
}
__device__ __forceinline__ float lrelu(float v){ return v >= 0.f ? v : 0.1f * v; }

template<int N>
__device__ __forceinline__ void ln_inlane(float* v, const float* g, const float* be, bool act){
  float mu = 0.f;
#pragma unroll
  for (int i = 0; i < N; ++i) mu += v[i];
  mu *= (1.f / N);
  float var = 0.f;
#pragma unroll
  for (int i = 0; i < N; ++i) { float d = v[i] - mu; var += d * d; }
  const float rs = rsqrtf(var * (1.f / N) + LEPS);
#pragma unroll
  for (int i = 0; i < N; ++i) {
    float y = (v[i] - mu) * rs * g[i] + be[i];
    v[i] = act ? lrelu(y) : y;
  }
}

// ============================================================================
// Kernel PREP: blocks [0,160) pack lin_w -> wpack; block 160 packs pe_w1 ->
// w1f B-frags (for the nets pe1 MFMA); blocks 161+ convert sparse_feats ->
// bf16.
// wpack fragment contract unchanged (verified since r1).
// w1f: B-frag for mfma_16x16x32: lane l elem e holds
//   B[k=(l>>4)*8+e][col=ct*16+(l&15)] = pe_w1[((l>>4)*8+e)*32 + ct*16 + (l&15)]
// at w1f[ct*512 + l*8 + e].
// ============================================================================
__global__ __launch_bounds__(256)
void pct_prep(const float* __restrict__ lin_w, unsigned short* __restrict__ wpack,
              const float* __restrict__ pe_w1, unsigned short* __restrict__ w1f,
              const float* __restrict__ sf, unsigned short* __restrict__ sfb16,
              const int n4)
{
  const int bid = blockIdx.x;
  if (bid < 160) {
    const int u    = bid * 256 + threadIdx.x;   // 0..40959
    const int lane = u & 63;
    const int tt   = (u >> 6) & 7;
    const int s    = u >> 9;
    const int ipb  = s * 32 + ((lane >> 4) * 8);
    const int nn   = tt * 16 + (lane & 15);
    unsigned short v[8];
#pragma unroll
    for (int j = 0; j < 8; ++j) {
      const int ip  = ipb + j;
      const int r   = ip & 3;
      const int ctl = (ip >> 2) & 1;
      const int qq  = (ip >> 3) & 3;
      const int c16 = (ip >> 5) & 15;
      const int P   = ip >> 9;
      const int c   = P * 32 + ctl * 16 + c16;
      const int m   = qq * 4 + r;
      v[j] = f2bf(lin_w[(long)(c * MM + m) * COUT + nn]);
    }
    *(uint4*)(wpack + (long)u * 8) = *(uint4*)v;
  } else if (bid == 160) {
    const int u = threadIdx.x;
    if (u < 128) {
      const int ct = u >> 6;
      const int l  = u & 63;
      unsigned short v[8];
#pragma unroll
      for (int e = 0; e < 8; ++e)
        v[e] = f2bf(pe_w1[((l >> 4) * 8 + e) * 32 + ct * 16 + (l & 15)]);
      *(uint4*)(w1f + (ct * 64 + l) * 8) = *(uint4*)v;
    }
  } else {
    const int i = (bid - 161) * 256 + threadIdx.x;
    if (i >= n4) return;
    const float4 v = ((const float4*)sf)[i];
    union { unsigned short us[4]; uint2 u; } r;
    r.us[0] = f2b(v.x); r.us[1] = f2b(v.y); r.us[2] = f2b(v.z); r.us[3] = f2b(v.w);
    ((uint2*)sfb16)[i] = r.u;
  }
}

// ============================================================================
// Kernel N: small nets + fragment PACK to fragw. r11 post-mortem restored
// this as a STANDALONE kernel (high occupancy; fusing under eg's 80KB LDS
// halved nets' waves and doubled its time).
// NEW: pe layer1 (the 1024-FMA + ~1024-LDS-read hot spot) now runs as
// 2 MFMAs per point: H staged bf16 to a per-wave padded LDS buffer (stride
// 40 ushorts), A-frag = 1 ds_read_b128/lane, B = w1f frags (global, packed
// by prep), LN applied on the verified D layout (row k=(l>>4)*4+r,
// col=l&15; rsum16 groups are fixed-k). Same-wave ds-write->ds-read is
// in-order (contract used since r2). wn layers remain scalar.
// ============================================================================
__global__ __launch_bounds__(256)
void pct_nets(
    const float* __restrict__ sparse_xyz,
    const int* __restrict__ nei_inds,
    const float* __restrict__ dense_xyz,
    const float* __restrict__ pe_w0, const float* __restrict__ pe_b0,
    const float* __restrict__ pe_g0, const float* __restrict__ pe_be0,
    const unsigned short* __restrict__ w1f, const float* __restrict__ pe_b1,
    const float* __restrict__ pe_g1, const float* __restrict__ pe_be1,
    const float* __restrict__ wn_w0, const float* __restrict__ wn_b0,
    const float* __restrict__ wn_g0, const float* __restrict__ wn_be0,
    const float* __restrict__ wn_w1, const float* __restrict__ wn_b1,
    const float* __restrict__ wn_g1, const float* __restrict__ wn_be1,
    const float* __restrict__ wn_w2, const float* __restrict__ wn_b2,
    const float* __restrict__ wn_g2, const float* __restrict__ wn_be2,
    unsigned short* __restrict__ fragw)
{
  __shared__ float sw[SW_TOTAL];                               // 3968 B
  __shared__ __align__(16) unsigned short wtsf[16 * 256];      // 8 KB A-frags
  __shared__ __align__(16) unsigned short pef[16 * 512];       // 16 KB [p][k][32c]
  __shared__ __align__(16) unsigned short hstage[4][16 * 40];  // 5 KB padded H

  const int t     = threadIdx.x;
  const int nbase = blockIdx.x * NPB;
  const int lane  = t & 63;
  const int wave  = t >> 6;

  // ---- stage net weights/params in LDS (pe_w1 now via w1f regs) ----
  for (int i = t; i < 96;   i += 256) sw[SW_PE_W0 + i] = pe_w0[i];
  for (int i = t; i < 32;   i += 256) {
    sw[SW_PE_B0 + i] = pe_b0[i];  sw[SW_PE_G0 + i] = pe_g0[i];  sw[SW_PE_BE0 + i] = pe_be0[i];
    sw[SW_PE_B1 + i] = pe_b1[i];  sw[SW_PE_G1 + i] = pe_g1[i];  sw[SW_PE_BE1 + i] = pe_be1[i];
  }
  for (int i = t; i < 48;   i += 256) sw[SW_WN_W0 + i] = wn_w0[i];
  for (int i = t; i < 16;   i += 256) {
    sw[SW_WN_B0 + i] = wn_b0[i];  sw[SW_WN_G0 + i] = wn_g0[i];  sw[SW_WN_BE0 + i] = wn_be0[i];
    sw[SW_WN_B1 + i] = wn_b1[i];  sw[SW_WN_G1 + i] = wn_g1[i];  sw[SW_WN_BE1 + i] = wn_be1[i];
    sw[SW_WN_B2 + i] = wn_b2[i];  sw[SW_WN_G2 + i] = wn_g2[i];  sw[SW_WN_BE2 + i] = wn_be2[i];
  }
  for (int i = t; i < 256;  i += 256) { sw[SW_WN_W1 + i] = wn_w1[i]; sw[SW_WN_W2 + i] = wn_w2[i]; }

  // W1 B-frags (wave-uniform layout, 2 uint4 regs)
  U16x8 w1b0, w1b1;
  w1b0.u4 = *(const uint4*)(w1f + lane * 8);
  w1b1.u4 = *(const uint4*)(w1f + 512 + lane * 8);
  __syncthreads();

  const int p  = t >> 4;     // point 0..15 (wave-local: p>>2 == wave)
  const int kk = t & 15;     // neighbor
  {
    const int n  = nbase + p;
    const int idx = nei_inds[n * KNN + kk];
    const float x0 = sparse_xyz[idx*3+0] - dense_xyz[n*3+0];
    const float x1 = sparse_xyz[idx*3+1] - dense_xyz[n*3+1];
    const float x2 = sparse_xyz[idx*3+2] - dense_xyz[n*3+2];

    // pe layer0 (3->32) + LN + act (scalar per-thread)
    float h[32];
#pragma unroll
    for (int c = 0; c < 32; ++c)
      h[c] = x0*sw[SW_PE_W0+c] + x1*sw[SW_PE_W0+32+c] + x2*sw[SW_PE_W0+64+c] + sw[SW_PE_B0+c];
    ln_inlane<32>(h, &sw[SW_PE_G0], &sw[SW_PE_BE0], true);

    // pe layer1 via MFMA, one point at a time within the wave
    union { unsigned short us[32]; uint4 u4[4]; } hb;
#pragma unroll
    for (int c = 0; c < 32; ++c) hb.us[c] = f2b(h[c]);

    const float g0  = sw[SW_PE_G1 + (lane & 15)];
    const float g1v = sw[SW_PE_G1 + 16 + (lane & 15)];
    const float be0 = sw[SW_PE_BE1 + (lane & 15)];
    const float be1 = sw[SW_PE_BE1 + 16 + (lane & 15)];
    const float b1lo = sw[SW_PE_B1 + (lane & 15)];
    const float b1hi = sw[SW_PE_B1 + 16 + (lane & 15)];
    unsigned short* hs = &hstage[wave][0];

#pragma unroll
    for (int i = 0; i < 4; ++i) {
      if ((p & 3) == i) {               // own point: stage H row kk
#pragma unroll
        for (int c4 = 0; c4 < 4; ++c4)
          *(uint4*)(hs + kk*40 + c4*8) = hb.u4[c4];
      }
      // A-frag: lane l holds H[row=l&15][j=(l>>4)*8..+8]
      U16x8 ha_;
      ha_.u4 = *(const uint4*)(hs + (lane & 15)*40 + (lane >> 4)*8);
      f32x4 z0 = {0.f,0.f,0.f,0.f}, z1 = {0.f,0.f,0.f,0.f};
      z0 = __builtin_amdgcn_mfma_f32_16x16x32_bf16(ha_.b, w1b0.b, z0, 0, 0, 0);
      z1 = __builtin_amdgcn_mfma_f32_16x16x32_bf16(ha_.b, w1b1.b, z1, 0, 0, 0);
      // + bias, then LN over 32 channels of row k=(lane>>4)*4+r
      unsigned short* pp_ = pef + (wave*4 + i) * 512;
#pragma unroll
      for (int r = 0; r < 4; ++r) {
        const float v0 = z0[r] + b1lo;
        const float v1 = z1[r] + b1hi;
        const float mu = rsum16(v0 + v1) * (1.f/32.f);
        const float d0 = v0 - mu, d1 = v1 - mu;
        const float qv = rsum16(d0*d0 + d1*d1);
        const float rsv = rsqrtf(qv * (1.f/32.f) + LEPS);
        const int krow = (lane >> 4)*4 + r;
        pp_[krow*32 + (lane & 15)]      = f2b(d0*rsv*g0 + be0);
        pp_[krow*32 + 16 + (lane & 15)] = f2b(d1*rsv*g1v + be1);
      }
    }

    // wn layer0 (3->16) + LN + act
    float w[16];
#pragma unroll
    for (int m = 0; m < 16; ++m)
      w[m] = x0*sw[SW_WN_W0+m] + x1*sw[SW_WN_W0+16+m] + x2*sw[SW_WN_W0+32+m] + sw[SW_WN_B0+m];
    ln_inlane<16>(w, &sw[SW_WN_G0], &sw[SW_WN_BE0], true);

    // wn layer1 (16->16) + LN + act
    float z2[16];
#pragma unroll
    for (int m = 0; m < 16; ++m) z2[m] = sw[SW_WN_B1 + m];
#pragma unroll 4
    for (int j = 0; j < 16; ++j) {
      const float wj = w[j];
#pragma unroll
      for (int m = 0; m < 16; ++m) z2[m] += wj * sw[SW_WN_W1 + j*16 + m];
    }
    ln_inlane<16>(z2, &sw[SW_WN_G1], &sw[SW_WN_BE1], true);

    // wn layer2 (16->16) + LN (no act)
#pragma unroll
    for (int m = 0; m < 16; ++m) w[m] = sw[SW_WN_B2 + m];
#pragma unroll 4
    for (int j = 0; j < 16; ++j) {
      const float wj = z2[j];
#pragma unroll
      for (int m = 0; m < 16; ++m) w[m] += wj * sw[SW_WN_W2 + j*16 + m];
    }
    ln_inlane<16>(w, &sw[SW_WN_G2], &sw[SW_WN_BE2], false);
    // A-fragment store: slot lane L=(kk>>3)*16+m holds wts[k=(L>>4)*8+j][m=L&15]
    {
      unsigned short* wf = wtsf + p*256 + ((kk >> 3) << 7) + (kk & 7);
#pragma unroll
      for (int m = 0; m < 16; ++m) wf[m*8] = f2b(w[m]);
    }
  }
  // NO barrier: wave w wrote wtsf/pef for points 4w..4w+3 and packs the same.

  // ---- pack phase: coalesced fragment stores into fragw ----
  {
    const int l2   = lane & 31;
    const int ct2  = lane >> 5;        // lanes<32 -> pe ct0 (+af), lanes>=32 -> pe ct1
#pragma unroll
    for (int i = 0; i < 4; ++i) {
      const int pp = wave*4 + i;
      unsigned short* fw = fragw + (size_t)(nbase + pp) * FRE;
      if (lane < 32) {
        const uint4 a = *(const uint4*)(wtsf + pp*256 + lane*8);
        *(uint4*)(fw + lane*8) = a;
      }
      union { unsigned short us[8]; uint4 u4; } o;
#pragma unroll
      for (int j = 0; j < 8; ++j)
        o.us[j] = pef[pp*512 + ((l2 >> 4)*8 + j)*32 + ct2*16 + (l2 & 15)];
      *(uint4*)(fw + 256 + ct2*256 + l2*8) = o.u4;
    }
  }
}

// ============================================================================
// Kernel EG (r8 VERBATIM — measured 111 us; r9 occupancy and r10 ILP edits
// both null-or-regress, so this is the pinned-best eg).
// ============================================================================
__global__ __launch_bounds__(256)
void pct_eg(
    const int* __restrict__ nei_inds,
    const unsigned short* __restrict__ sfb16,
    const unsigned short* __restrict__ fragw,
    const unsigned short* __restrict__ wpack,
    const float* __restrict__ lin_b, const float* __restrict__ lin_g,
    const float* __restrict__ lin_be, const float* __restrict__ dense_feats,
    float* __restrict__ out)
{
  __shared__ __align__(16) union FU {
    unsigned short feats[16][2048];   // [p][16k][128c] bf16, 64 KB
    float outs[16][132];              // epilogue tile (aliased; barriered)
  } fu;
  __shared__ __align__(16) unsigned short aL[16][512];   // 16 KB bridge

  const int t     = threadIdx.x;
  const int nbase = blockIdx.x * NPB;
  const int lane  = t & 63;
  const int wave  = t >> 6;
  const int q     = lane >> 4;      // 0..3
  const int mq    = lane & 15;

  int idxall[4][4];
#pragma unroll
  for (int i = 0; i < 4; ++i)
#pragma unroll
    for (int t4 = 0; t4 < 4; ++t4)
      idxall[i][t4] = nei_inds[(nbase + wave*4 + i) * KNN + t4*4 + q];

  U16x8 af[4], pe0[4], pe1[4];
  const uint4 zero4 = {0u, 0u, 0u, 0u};
#pragma unroll
  for (int i = 0; i < 4; ++i) {
    const int p = wave*4 + i;
#pragma unroll
    for (int t4 = 0; t4 < 4; ++t4)
      __builtin_amdgcn_global_load_lds(
          (const void*)(sfb16 + (size_t)idxall[i][t4] * CIN + mq * 8),
          (void*)((char*)fu.feats[p] + t4 * 1024), 16, 0, 0);
    const unsigned short* fw = fragw + (size_t)(nbase + p) * FRE;
    af[i].u4  = (lane < 32) ? *(const uint4*)(fw + lane*8) : zero4;
    pe0[i].u4 = *(const uint4*)(fw + 256 + (lane & 31)*8);
    pe1[i].u4 = *(const uint4*)(fw + 512 + (lane & 31)*8);
  }
  __syncthreads();

  f32x4 acc0 = {0.f,0.f,0.f,0.f}, acc1 = {0.f,0.f,0.f,0.f};
  const unsigned short* wpl = wpack + ((size_t)(wave*2) * 64 + lane) * 8;

#pragma unroll 1
  for (int P = 0; P < 5; ++P) {
#pragma unroll
    for (int i = 0; i < 4; ++i) {
      const int p = wave*4 + i;
      f32x4 a0 = {0.f,0.f,0.f,0.f}, a1 = {0.f,0.f,0.f,0.f};
      if (P < 4) {
        const unsigned short* sb = &fu.feats[p][0] + (q & 1) * 1024 + mq;
        U16x8 b0_, b1_;
#pragma unroll
        for (int j = 0; j < 8; ++j) b0_.us[j] = sb[j * CIN + (2*P    ) * 16];
#pragma unroll
        for (int j = 0; j < 8; ++j) b1_.us[j] = sb[j * CIN + (2*P + 1) * 16];
        a0 = __builtin_amdgcn_mfma_f32_16x16x32_bf16(af[i].b, b0_.b, a0, 0, 0, 0);
        a1 = __builtin_amdgcn_mfma_f32_16x16x32_bf16(af[i].b, b1_.b, a1, 0, 0, 0);
      } else {
        a0 = __builtin_amdgcn_mfma_f32_16x16x32_bf16(af[i].b, pe0[i].b, a0, 0, 0, 0);
        a1 = __builtin_amdgcn_mfma_f32_16x16x32_bf16(af[i].b, pe1[i].b, a1, 0, 0, 0);
      }
      union { unsigned short us[8]; uint4 u4; } o;
#pragma unroll
      for (int r = 0; r < 4; ++r) { o.us[r] = f2b(a0[r]); o.us[4+r] = f2b(a1[r]); }
      *(uint4*)((char*)aL[p] + ((mq*64 + q*16) ^ ((p & 7) << 4))) = o.u4;
    }
    __syncthreads();

#pragma unroll
    for (int s = 0; s < 16; ++s) {
      const int sg = P*16 + s;
      U16x8 af2;
      af2.u4 = *(const uint4*)((char*)aL[mq] + ((s*64 + q*16) ^ ((mq & 7) << 4)));
      const unsigned short* wpb = wpl + (size_t)sg * 4096;
      U16x8 b0_, b1_;
      b0_.u4 = *(const uint4*)(wpb);
      b1_.u4 = *(const uint4*)(wpb + 512);
      acc0 = __builtin_amdgcn_mfma_f32_16x16x32_bf16(af2.b, b0_.b, acc0, 0, 0, 0);
      acc1 = __builtin_amdgcn_mfma_f32_16x16x32_bf16(af2.b, b1_.b, acc1, 0, 0, 0);
    }
    __syncthreads();
  }

#pragma unroll
  for (int r = 0; r < 4; ++r) {
    fu.outs[q*4 + r][(wave*2    )*16 + mq] = acc0[r];
    fu.outs[q*4 + r][(wave*2 + 1)*16 + mq] = acc1[r];
  }
  __syncthreads();

  {
    const int p   = t >> 4;
    const int l16 = t & 15;
    const int n   = nbase + p;
    float v[8];
#pragma unroll
    for (int i = 0; i < 2; ++i) {
      const int cb = (i*16 + l16) * 4;
      const float4 r  = *(const float4*)(&fu.outs[p][cb]);
      const float4 bb = *(const float4*)(lin_b + cb);
      v[i*4+0] = r.x + bb.x; v[i*4+1] = r.y + bb.y;
      v[i*4+2] = r.z + bb.z; v[i*4+3] = r.w + bb.w;
    }
    float sum = 0.f;
#pragma unroll
    for (int i = 0; i < 8; ++i) sum += v[i];
    const float mu = rsum16(sum) * (1.f/128.f);
    float qs = 0.f;
#pragma unroll
    for (int i = 0; i < 8; ++i) { float d = v[i] - mu; qs += d*d; }
    const float rs = rsqrtf(rsum16(qs) * (1.f/128.f) + LEPS);
#pragma unroll
    for (int i = 0; i < 2; ++i) {
      const int cb = (i*16 + l16) * 4;
      const float4 g  = *(const float4*)(lin_g  + cb);
      const float4 be = *(const float4*)(lin_be + cb);
      const float4 df = *(const float4*)(dense_feats + (long)n*COUT + cb);
      float4 y;
      y.x = lrelu((v[i*4+0]-mu)*rs*g.x + be.x) + df.x;
      y.y = lrelu((v[i*4+1]-mu)*rs*g.y + be.y) + df.y;
      y.z = lrelu((v[i*4+2]-mu)*rs*g.z + be.z) + df.z;
      y.w = lrelu((v[i*4+3]-mu)*rs*g.w + be.w) + df.w;
      *(float4*)(out + (long)n*COUT + cb) = y;
    }
  }
}

// ============================================================================
// Last-resort fallback: fully-fused kernel (used if ws_size is too small)
// ============================================================================
__global__ __launch_bounds__(256)
void pct_fused(
    const float* __restrict__ sparse_xyz,
    const float* __restrict__ sparse_feats,
    const int* __restrict__ nei_inds,
    const float* __restrict__ dense_xyz,
    const float* __restrict__ dense_feats,
    const float* __restrict__ pe_w0, const float* __restrict__ pe_b0,
    const float* __restrict__ pe_g0, const float* __restrict__ pe_be0,
    const float* __restrict__ pe_w1, const float* __restrict__ pe_b1,
    const float* __restrict__ pe_g1, const float* __restrict__ pe_be1,
    const float* __restrict__ wn_w0, const float* __restrict__ wn_b0,
    const float* __restrict__ wn_g0, const float* __restrict__ wn_be0,
    const float* __restrict__ wn_w1, const float* __restrict__ wn_b1,
    const float* __restrict__ wn_g1, const float* __restrict__ wn_be1,
    const float* __restrict__ wn_w2, const float* __restrict__ wn_b2,
    const float* __restrict__ wn_g2, const float* __restrict__ wn_be2,
    const float* __restrict__ lin_w, const float* __restrict__ lin_b,
    const float* __restrict__ lin_g, const float* __restrict__ lin_be,
    float* __restrict__ out)
{
  __shared__ __align__(16) unsigned short feat_s[KNN][CF];
  __shared__ float wts_s[KNN][MM];
  __shared__ float loc_s[KNN][3];
  __shared__ int   nei_s[KNN];
  __shared__ __align__(16) unsigned short out_tile[CF*MM][8];

  const int t  = threadIdx.x;
  const int n0 = blockIdx.x * 8;
  const int k  = t >> 4;
  const int l  = t & 15;

#pragma unroll 1
  for (int p = 0; p < 8; ++p) {
    const int n = n0 + p;
    if (t < KNN) {
      int idx = nei_inds[n*KNN + t];
      nei_s[t] = idx;
      loc_s[t][0] = sparse_xyz[idx*3+0] - dense_xyz[n*3+0];
      loc_s[t][1] = sparse_xyz[idx*3+1] - dense_xyz[n*3+1];
      loc_s[t][2] = sparse_xyz[idx*3+2] - dense_xyz[n*3+2];
    }
    __syncthreads();
    {
      const int gk = t >> 4;
      const int c8 = (t & 15) * 8;
      const float* src = sparse_feats + (long)nei_s[gk]*CIN + c8;
      const float4 va = *(const float4*)(src);
      const float4 vb = *(const float4*)(src + 4);
      unsigned short* dst = &feat_s[gk][c8];
      dst[0] = f2bf(va.x); dst[1] = f2bf(va.y); dst[2] = f2bf(va.z); dst[3] = f2bf(va.w);
      dst[4] = f2bf(vb.x); dst[5] = f2bf(vb.y); dst[6] = f2bf(vb.z); dst[7] = f2bf(vb.w);
    }
    const float x0 = loc_s[k][0], x1 = loc_s[k][1], x2 = loc_s[k][2];
    const int c0 = l, c1 = l + 16;
    float ha = x0*pe_w0[0*PEC+c0] + x1*pe_w0[1*PEC+c0] + x2*pe_w0[2*PEC+c0] + pe_b0[c0];
    float hb = x0*pe_w0[0*PEC+c1] + x1*pe_w0[1*PEC+c1] + x2*pe_w0[2*PEC+c1] + pe_b0[c1];
    {
      float mu = rsum16(ha + hb) * (1.f/32.f);
      float da = ha - mu, db = hb - mu;
      float q  = rsum16(da*da + db*db);
      float rs = rsqrtf(q*(1.f/32.f) + LEPS);
      ha = lrelu(da*rs*pe_g0[c0] + pe_be0[c0]);
      hb = lrelu(db*rs*pe_g0[c1] + pe_be0[c1]);
    }
    float za = pe_b1[c0], zb = pe_b1[c1];
#pragma unroll
    for (int j = 0; j < 16; ++j) {
      float va = __shfl(ha, j, 16);
      float vb = __shfl(hb, j, 16);
      za += va * pe_w1[j*PEC + c0] + vb * pe_w1[(j+16)*PEC + c0];
      zb += va * pe_w1[j*PEC + c1] + vb * pe_w1[(j+16)*PEC + c1];
    }
    {
      float mu = rsum16(za + zb) * (1.f/32.f);
      float da = za - mu, db = zb - mu;
      float q  = rsum16(da*da + db*db);
      float rs = rsqrtf(q*(1.f/32.f) + LEPS);
      feat_s[k][CIN + c0] = f2bf(da*rs*pe_g1[c0] + pe_be1[c0]);
      feat_s[k][CIN + c1] = f2bf(db*rs*pe_g1[c1] + pe_be1[c1]);
    }
    float w0v = x0*wn_w0[0*MM+l] + x1*wn_w0[1*MM+l] + x2*wn_w0[2*MM+l] + wn_b0[l];
    {
      float mu = rsum16(w0v) * (1.f/16.f);
      float d  = w0v - mu;
      float rs = rsqrtf(rsum16(d*d)*(1.f/16.f) + LEPS);
      w0v = lrelu(d*rs*wn_g0[l] + wn_be0[l]);
    }
    float w1v = wn_b1[l];
#pragma unroll
    for (int j = 0; j < 16; ++j)
      w1v += __shfl(w0v, j, 16) * wn_w1[j*MM + l];
    {
      float mu = rsum16(w1v) * (1.f/16.f);
      float d  = w1v - mu;
      float rs = rsqrtf(rsum16(d*d)*(1.f/16.f) + LEPS);
      w1v = lrelu(d*rs*wn_g1[l] + wn_be1[l]);
    }
    float w2v = wn_b2[l];
#pragma unroll
    for (int j = 0; j < 16; ++j)
      w2v += __shfl(w1v, j, 16) * wn_w2[j*MM + l];
    {
      float mu = rsum16(w2v) * (1.f/16.f);
      float d  = w2v - mu;
      float rs = rsqrtf(rsum16(d*d)*(1.f/16.f) + LEPS);
      w2v = d*rs*wn_g2[l] + wn_be2[l];
    }
    wts_s[k][l] = w2v;
    __syncthreads();
    {
      const int m = t & 15;
      const int g = t >> 4;
      float wv[KNN];
#pragma unroll
      for (int kk = 0; kk < KNN; ++kk) wv[kk] = wts_s[kk][m];
#pragma unroll
      for (int j = 0; j < 10; ++j) {
        const int c = g*10 + j;
        float acc = 0.f;
#pragma unroll
        for (int kk = 0; kk < KNN; ++kk)
          acc += bf2f(feat_s[kk][c]) * wv[kk];
        out_tile[c*MM + m][p] = f2bf(acc);
      }
    }
    __syncthreads();
  }
  {
    const int h  = t >> 6;
    const int o0 = (t & 63) * 2;
    float acc0[8], acc1[8];
#pragma unroll
    for (int p = 0; p < 8; ++p) { acc0[p] = 0.f; acc1[p] = 0.f; }
    const int i0 = h * 640;
    for (int i = i0; i < i0 + 640; ++i) {
      const float2 wv = *(const float2*)(lin_w + (long)i*COUT + o0);
      const float wa = wv.x;
      const float wc = wv.y;
      const uint4 r = *(const uint4*)(&out_tile[i][0]);
      const float f0 = bf2f((unsigned short)(r.x & 0xffffu));
      const float f1 = bf2f((unsigned short)(r.x >> 16));
      const float g2 = bf2f((unsigned short)(r.y & 0xffffu));
      const float g3 = bf2f((unsigned short)(r.y >> 16));
      const float g4 = bf2f((unsigned short)(r.z & 0xffffu));
      const float g5 = bf2f((unsigned short)(r.z >> 16));
      const float g6 = bf2f((unsigned short)(r.w & 0xffffu));
      const float g7 = bf2f((unsigned short)(r.w >> 16));
      acc0[0] += f0*wa; acc1[0] += f0*wc;
      acc0[1] += f1*wa; acc1[1] += f1*wc;
      acc0[2] += g2*wa; acc1[2] += g2*wc;
      acc0[3] += g3*wa; acc1[3] += g3*wc;
      acc0[4] += g4*wa; acc1[4] += g4*wc;
      acc0[5] += g5*wa; acc1[5] += g5*wc;
      acc0[6] += g6*wa; acc1[6] += g6*wc;
      acc0[7] += g7*wa; acc1[7] += g7*wc;
    }
    __syncthreads();
    float* red = (float*)&out_tile[0][0];
#pragma unroll
    for (int p = 0; p < 8; ++p) {
      red[((h*8 + p) << 7) + o0    ] = acc0[p];
      red[((h*8 + p) << 7) + o0 + 1] = acc1[p];
    }
    __syncthreads();
    const int p2 = t >> 5, l2 = t & 31;
    const int n  = n0 + p2;
    float v[4];
#pragma unroll
    for (int j = 0; j < 4; ++j) {
      const int o = l2 + (j << 5);
      float sv = red[((0*8 + p2) << 7) + o] + red[((1*8 + p2) << 7) + o]
               + red[((2*8 + p2) << 7) + o] + red[((3*8 + p2) << 7) + o];
      v[j] = sv + lin_b[o];
    }
    float mu = rsum32(v[0] + v[1] + v[2] + v[3]) * (1.f/128.f);
    float q = 0.f;
#pragma unroll
    for (int j = 0; j < 4; ++j) { float d = v[j] - mu; q += d*d; }
    float rs = rsqrtf(rsum32(q) * (1.f/128.f) + LEPS);
#pragma unroll
    for (int j = 0; j < 4; ++j) {
      const int o = l2 + (j << 5);
      float y = (v[j] - mu) * rs * lin_g[o] + lin_be[o];
      y = lrelu(y);
      y += dense_feats[n*COUT + o];
      out[n*COUT + o] = y;
    }
  }
}

extern "C" void kernel_launch(void* const* d_in, const int* in_sizes, int n_in,
                              void* d_out, int out_size, void* d_ws, size_t ws_size,
                              hipStream_t stream) {
  const int Nd = in_sizes[2] / KNN;    // 40000
  const int Ns = in_sizes[1] / CIN;    // 10000
  const size_t fr_bytes = (size_t)Nd * FRE * 2;        // 61.44 MB
  const size_t w_bytes  = (size_t)KDIM * COUT * 2;     // 655 KB
  const size_t w1_bytes = 4096;                        // w1f (2KB used)
  const size_t f_bytes  = (size_t)Ns * CIN * 2;        // 2.56 MB
  const bool use_split = (ws_size >= fr_bytes + w_bytes + w1_bytes + f_bytes)
                         && (Nd % NPB == 0) && ((Ns * CIN) % 4 == 0);

  if (use_split) {
    unsigned short* fragw = (unsigned short*)d_ws;
    unsigned short* wpack = (unsigned short*)((char*)d_ws + fr_bytes);
    unsigned short* w1f   = (unsigned short*)((char*)d_ws + fr_bytes + w_bytes);
    unsigned short* sfb16 = (unsigned short*)((char*)d_ws + fr_bytes + w_bytes + w1_bytes);

    const int n4 = Ns * CIN / 4;
    pct_prep<<<dim3(161 + (n4 + 255)/256), dim3(256), 0, stream>>>(
      (const float*)d_in[27], wpack, (const float*)d_in[11], w1f,
      (const float*)d_in[1], sfb16, n4);

    pct_nets<<<dim3(Nd / NPB), dim3(256), 0, stream>>>(
      (const float*)d_in[0],  (const int*)d_in[2],  (const float*)d_in[4],
      (const float*)d_in[7],  (const float*)d_in[8],  (const float*)d_in[9],  (const float*)d_in[10],
      w1f,                    (const float*)d_in[12], (const float*)d_in[13], (const float*)d_in[14],
      (const float*)d_in[15], (const float*)d_in[16], (const float*)d_in[17], (const float*)d_in[18],
      (const float*)d_in[19], (const float*)d_in[20], (const float*)d_in[21], (const float*)d_in[22],
      (const float*)d_in[23], (const float*)d_in[24], (const float*)d_in[25], (const float*)d_in[26],
      fragw);

    pct_eg<<<dim3(Nd / NPB), dim3(256), 0, stream>>>(
      (const int*)d_in[2], sfb16, fragw, wpack,
      (const float*)d_in[28], (const float*)d_in[29], (const float*)d_in[30],
      (const float*)d_in[6], (float*)d_out);
  } else {
    pct_fused<<<dim3(Nd / 8), dim3(256), 0, stream>>>(
      (const float*)d_in[0],  (const float*)d_in[1],  (const int*)d_in[2],
      (const float*)d_in[4],  (const float*)d_in[6],
      (const float*)d_in[7],  (const float*)d_in[8],  (const float*)d_in[9],  (const float*)d_in[10],
      (const float*)d_in[11], (const float*)d_in[12], (const float*)d_in[13], (const float*)d_in[14],
      (const float*)d_in[15], (const float*)d_in[16], (const float*)d_in[17], (const float*)d_in[18],
      (const float*)d_in[19], (const float*)d_in[20], (const float*)d_in[21], (const float*)d_in[22],
      (const float*)d_in[23], (const float*)d_in[24], (const float*)d_in[25], (const float*)d_in[26],
      (const float*)d_in[27], (const float*)d_in[28], (const float*)d_in[29], (const float*)d_in[30],
      (float*)d_out);
  }
}